// Round 1
// baseline (5599.219 us; speedup 1.0000x reference)
//
#include <hip/hip_runtime.h>

#define N_NODES   100000
#define N_EDGES   3200000
#define NUM_GRAPHS 1024
#define F_IN      128
#define EMB       32

// ---- monotonic float<->uint encoding for atomicMax on signed floats ----
__device__ __forceinline__ unsigned encf(float f) {
    unsigned u = __float_as_uint(f);
    return (u & 0x80000000u) ? ~u : (u | 0x80000000u);
}
__device__ __forceinline__ float decf(unsigned u) {
    u = (u & 0x80000000u) ? (u ^ 0x80000000u) : ~u;
    return __uint_as_float(u);
}
// encf(-inf) = ~0xFF800000 = 0x007FFFFF
#define ENC_NEG_INF 0x007FFFFFu

// ---- init: zero degree counts, set pooled accumulators to encoded -inf ----
__global__ void init_k(int* __restrict__ deg, unsigned* __restrict__ pooledU) {
    int i = blockIdx.x * blockDim.x + threadIdx.x;
    if (i < N_NODES) deg[i] = 0;
    if (i < NUM_GRAPHS * EMB) pooledU[i] = ENC_NEG_INF;
}

// ---- degree: count incoming edges per node ----
__global__ void degree_k(const int* __restrict__ dst, int* __restrict__ deg) {
    int e = blockIdx.x * blockDim.x + threadIdx.x;
    if (e < N_EDGES) atomicAdd(&deg[dst[e]], 1);
}

// ---- dinv = rsqrt(deg + 1)  (+1 = self-loop; always >= 1) ----
__global__ void dinv_k(const int* __restrict__ deg, float* __restrict__ dinv) {
    int n = blockIdx.x * blockDim.x + threadIdx.x;
    if (n < N_NODES) dinv[n] = rsqrtf((float)(deg[n] + 1));
}

// ---- layer 0 transform: tmp[n][j] = (x[n,:] @ W0[:,j]) * dinv[n]; agg init = tmp (self-loop) ----
__global__ void transform0_k(const float* __restrict__ x, const float* __restrict__ W0,
                             const float* __restrict__ dinv,
                             float* __restrict__ tmp, float* __restrict__ agg) {
    int i = blockIdx.x * blockDim.x + threadIdx.x;
    if (i >= N_NODES * EMB) return;
    int n = i >> 5, j = i & 31;
    const float* xr = x + (long long)n * F_IN;
    float acc = 0.f;
#pragma unroll 8
    for (int k = 0; k < F_IN; ++k) acc += xr[k] * W0[k * EMB + j];
    float v = acc * dinv[n];
    tmp[i] = v;
    agg[i] = v;
}

// ---- hidden transform: tmp[n][j] = (h[n,:] @ W[:,j]) * dinv[n]; agg init = tmp ----
__global__ void transform_k(const float* __restrict__ h, const float* __restrict__ W,
                            const float* __restrict__ dinv,
                            float* __restrict__ tmp, float* __restrict__ agg) {
    int i = blockIdx.x * blockDim.x + threadIdx.x;
    if (i >= N_NODES * EMB) return;
    int n = i >> 5, j = i & 31;
    const float* hr = h + n * EMB;
    float acc = 0.f;
#pragma unroll
    for (int k = 0; k < EMB; ++k) acc += hr[k] * W[k * EMB + j];
    float v = acc * dinv[n];
    tmp[i] = v;
    agg[i] = v;
}

// ---- edge scatter: agg[dst] += tmp[src]  (8 threads/edge, float4 each) ----
__global__ void scatter_k(const int* __restrict__ src, const int* __restrict__ dst,
                          const float* __restrict__ tmp, float* __restrict__ agg) {
    int i = blockIdx.x * blockDim.x + threadIdx.x;
    if (i >= N_EDGES * 8) return;
    int e = i >> 3, q = i & 7;
    int s = src[e], d = dst[e];
    float4 v = *(const float4*)(tmp + s * EMB + q * 4);
    float* a = agg + d * EMB + q * 4;
    unsafeAtomicAdd(a + 0, v.x);
    unsafeAtomicAdd(a + 1, v.y);
    unsafeAtomicAdd(a + 2, v.z);
    unsafeAtomicAdd(a + 3, v.w);
}

// ---- finalize: h[n][j] = leaky_relu(agg[n][j]*dinv[n] + b[j], 0.01) ----
__global__ void finalize_k(const float* __restrict__ agg, const float* __restrict__ dinv,
                           const float* __restrict__ b, float* __restrict__ h) {
    int i = blockIdx.x * blockDim.x + threadIdx.x;
    if (i >= N_NODES * EMB) return;
    int n = i >> 5, j = i & 31;
    float v = agg[i] * dinv[n] + b[j];
    h[i] = v > 0.f ? v : 0.01f * v;
}

// ---- global max pool via encoded atomicMax ----
__global__ void pool_k(const float* __restrict__ h, const int* __restrict__ batch,
                       unsigned* __restrict__ pooledU) {
    int i = blockIdx.x * blockDim.x + threadIdx.x;
    if (i >= N_NODES * EMB) return;
    int n = i >> 5, c = i & 31;
    atomicMax(&pooledU[batch[n] * EMB + c], encf(h[i]));
}

// ---- head: decode pooled, write pooled to out[1024:], out[g] = pooled[g,:]@Wout + bout ----
__global__ void out_k(const unsigned* __restrict__ pooledU, const float* __restrict__ Wout,
                      const float* __restrict__ bout, float* __restrict__ out) {
    int i = blockIdx.x * blockDim.x + threadIdx.x;
    if (i >= NUM_GRAPHS * EMB) return;
    int g = i >> 5, c = i & 31;
    float v = decf(pooledU[i]);
    out[NUM_GRAPHS + i] = v;       // pooled output, row-major [1024,32]
    float p = v * Wout[c];
#pragma unroll
    for (int o = 16; o > 0; o >>= 1) p += __shfl_xor(p, o, 32);
    if (c == 0) out[g] = p + bout[0];
}

extern "C" void kernel_launch(void* const* d_in, const int* in_sizes, int n_in,
                              void* d_out, int out_size, void* d_ws, size_t ws_size,
                              hipStream_t stream) {
    const float* x     = (const float*)d_in[0];
    const int*   ei    = (const int*)d_in[1];     // [2, E] int
    const int*   src   = ei;
    const int*   dst   = ei + N_EDGES;
    const int*   batch = (const int*)d_in[2];
    const float* W0    = (const float*)d_in[3];   // [128,32]
    const float* b0    = (const float*)d_in[4];   // [32]
    const float* Ws    = (const float*)d_in[5];   // [3,32,32]
    const float* bs    = (const float*)d_in[6];   // [3,32]
    const float* Wout  = (const float*)d_in[7];   // [32,1]
    const float* bout  = (const float*)d_in[8];   // [1]
    float* out = (float*)d_out;

    char* ws = (char*)d_ws;
    int*      deg     = (int*)ws;        ws += (size_t)N_NODES * 4;          // 400000 B (16B-mult)
    float*    dinv    = (float*)ws;      ws += (size_t)N_NODES * 4;          // 400000 B
    float*    tmp     = (float*)ws;      ws += (size_t)N_NODES * EMB * 4;    // 12.8 MB
    float*    agg     = (float*)ws;      ws += (size_t)N_NODES * EMB * 4;    // 12.8 MB
    float*    h       = (float*)ws;      ws += (size_t)N_NODES * EMB * 4;    // 12.8 MB
    unsigned* pooledU = (unsigned*)ws;   ws += (size_t)NUM_GRAPHS * EMB * 4; // 128 KB

    const int B = 256;
    const int NE_g  = (N_EDGES + B - 1) / B;
    const int NC_g  = (N_NODES * EMB + B - 1) / B;      // node*channel grid
    const int SC_g  = (N_EDGES * 8 + B - 1) / B;        // scatter grid
    const int NN_g  = (N_NODES + B - 1) / B;

    init_k<<<NN_g, B, 0, stream>>>(deg, pooledU);
    degree_k<<<NE_g, B, 0, stream>>>(dst, deg);
    dinv_k<<<NN_g, B, 0, stream>>>(deg, dinv);

    // layer 0: 128 -> 32
    transform0_k<<<NC_g, B, 0, stream>>>(x, W0, dinv, tmp, agg);
    scatter_k<<<SC_g, B, 0, stream>>>(src, dst, tmp, agg);
    finalize_k<<<NC_g, B, 0, stream>>>(agg, dinv, b0, h);

    // hidden layers: 32 -> 32
    for (int l = 0; l < 3; ++l) {
        transform_k<<<NC_g, B, 0, stream>>>(h, Ws + l * EMB * EMB, dinv, tmp, agg);
        scatter_k<<<SC_g, B, 0, stream>>>(src, dst, tmp, agg);
        finalize_k<<<NC_g, B, 0, stream>>>(agg, dinv, bs + l * EMB, h);
    }

    pool_k<<<NC_g, B, 0, stream>>>(h, batch, pooledU);
    out_k<<<(NUM_GRAPHS * EMB + B - 1) / B, B, 0, stream>>>(pooledU, Wout, bout, out);
}

// Round 2
// 1407.787 us; speedup vs baseline: 3.9773x; 3.9773x over previous
//
#include <hip/hip_runtime.h>

#define N_NODES   100000
#define N_EDGES   3200000
#define NUM_GRAPHS 1024
#define F_IN      128
#define EMB       32

// ---- monotonic float<->uint encoding for atomicMax on signed floats ----
__device__ __forceinline__ unsigned encf(float f) {
    unsigned u = __float_as_uint(f);
    return (u & 0x80000000u) ? ~u : (u | 0x80000000u);
}
__device__ __forceinline__ float decf(unsigned u) {
    u = (u & 0x80000000u) ? (u ^ 0x80000000u) : ~u;
    return __uint_as_float(u);
}
#define ENC_NEG_INF 0x007FFFFFu

// ---- init: zero degree counts, set pooled accumulators to encoded -inf ----
__global__ void init_k(int* __restrict__ deg, unsigned* __restrict__ pooledU) {
    int i = blockIdx.x * blockDim.x + threadIdx.x;
    if (i < N_NODES) deg[i] = 0;
    if (i < NUM_GRAPHS * EMB) pooledU[i] = ENC_NEG_INF;
}

// ---- degree: count incoming edges per node ----
__global__ void degree_k(const int* __restrict__ dst, int* __restrict__ deg) {
    int e = blockIdx.x * blockDim.x + threadIdx.x;
    if (e < N_EDGES) atomicAdd(&deg[dst[e]], 1);
}

// ---- single-workgroup exclusive scan of deg -> row_ptr; also pos=row_ptr, dinv ----
#define SCAN_T 1024
#define SCAN_CH 98   // ceil(100000/1024)
__global__ __launch_bounds__(1024) void scan_k(const int* __restrict__ deg,
                                               int* __restrict__ row_ptr,
                                               int* __restrict__ pos,
                                               float* __restrict__ dinv) {
    __shared__ int part[SCAN_T];
    int t = threadIdx.x;
    int base = t * SCAN_CH;
    int s = 0;
    for (int i = 0; i < SCAN_CH; ++i) {
        int idx = base + i;
        if (idx < N_NODES) s += deg[idx];
    }
    part[t] = s;
    __syncthreads();
    // Hillis-Steele inclusive scan over 1024 partials
    for (int off = 1; off < SCAN_T; off <<= 1) {
        int v = part[t];
        int add = (t >= off) ? part[t - off] : 0;
        __syncthreads();
        part[t] = v + add;
        __syncthreads();
    }
    int run = (t > 0) ? part[t - 1] : 0;   // exclusive prefix of this chunk
    for (int i = 0; i < SCAN_CH; ++i) {
        int idx = base + i;
        if (idx < N_NODES) {
            row_ptr[idx] = run;
            pos[idx] = run;
            dinv[idx] = rsqrtf((float)(deg[idx] + 1));
            run += deg[idx];
        }
    }
    if (t == SCAN_T - 1) row_ptr[N_NODES] = run;   // run == total here
}

// ---- CSR fill: col[pos[dst[e]]++] = src[e] ----
__global__ void fill_k(const int* __restrict__ src, const int* __restrict__ dst,
                       int* __restrict__ pos, int* __restrict__ col) {
    int e = blockIdx.x * blockDim.x + threadIdx.x;
    if (e < N_EDGES) {
        int idx = atomicAdd(&pos[dst[e]], 1);
        col[idx] = src[e];
    }
}

// ---- layer 0 transform: tmp[n][j] = (x[n,:] @ W0[:,j]) * dinv[n] ----
__global__ void transform0_k(const float* __restrict__ x, const float* __restrict__ W0,
                             const float* __restrict__ dinv, float* __restrict__ tmp) {
    int i = blockIdx.x * blockDim.x + threadIdx.x;
    if (i >= N_NODES * EMB) return;
    int n = i >> 5, j = i & 31;
    const float* xr = x + (long long)n * F_IN;
    float acc = 0.f;
#pragma unroll 8
    for (int k = 0; k < F_IN; ++k) acc += xr[k] * W0[k * EMB + j];
    tmp[i] = acc * dinv[n];
}

// ---- hidden transform: tmp[n][j] = (h[n,:] @ W[:,j]) * dinv[n] ----
__global__ void transform_k(const float* __restrict__ h, const float* __restrict__ W,
                            const float* __restrict__ dinv, float* __restrict__ tmp) {
    int i = blockIdx.x * blockDim.x + threadIdx.x;
    if (i >= N_NODES * EMB) return;
    int n = i >> 5, j = i & 31;
    const float* hr = h + n * EMB;
    float acc = 0.f;
#pragma unroll
    for (int k = 0; k < EMB; ++k) acc += hr[k] * W[k * EMB + j];
    tmp[i] = acc * dinv[n];
}

// ---- gather aggregate + finalize: h = leaky(dinv[n]*(tmp[n] + sum_in tmp[s]) + b) ----
__global__ void gather_k(const int* __restrict__ row_ptr, const int* __restrict__ col,
                         const float4* __restrict__ tmp4, const float* __restrict__ dinv,
                         const float* __restrict__ b, float4* __restrict__ h4) {
    int i = blockIdx.x * blockDim.x + threadIdx.x;
    if (i >= N_NODES * 8) return;
    int n = i >> 3, q = i & 7;
    int beg = row_ptr[n], end = row_ptr[n + 1];
    float4 acc = tmp4[i];              // self-loop term
    int k = beg;
    for (; k + 4 <= end; k += 4) {
        int s0 = col[k], s1 = col[k + 1], s2 = col[k + 2], s3 = col[k + 3];
        float4 v0 = tmp4[s0 * 8 + q];
        float4 v1 = tmp4[s1 * 8 + q];
        float4 v2 = tmp4[s2 * 8 + q];
        float4 v3 = tmp4[s3 * 8 + q];
        acc.x += (v0.x + v1.x) + (v2.x + v3.x);
        acc.y += (v0.y + v1.y) + (v2.y + v3.y);
        acc.z += (v0.z + v1.z) + (v2.z + v3.z);
        acc.w += (v0.w + v1.w) + (v2.w + v3.w);
    }
    for (; k < end; ++k) {
        int s = col[k];
        float4 v = tmp4[s * 8 + q];
        acc.x += v.x; acc.y += v.y; acc.z += v.z; acc.w += v.w;
    }
    float dn = dinv[n];
    float4 bb = ((const float4*)b)[q];
    float4 r;
    r.x = acc.x * dn + bb.x;
    r.y = acc.y * dn + bb.y;
    r.z = acc.z * dn + bb.z;
    r.w = acc.w * dn + bb.w;
    r.x = r.x > 0.f ? r.x : 0.01f * r.x;
    r.y = r.y > 0.f ? r.y : 0.01f * r.y;
    r.z = r.z > 0.f ? r.z : 0.01f * r.z;
    r.w = r.w > 0.f ? r.w : 0.01f * r.w;
    h4[i] = r;
}

// ---- global max pool via encoded atomicMax ----
__global__ void pool_k(const float* __restrict__ h, const int* __restrict__ batch,
                       unsigned* __restrict__ pooledU) {
    int i = blockIdx.x * blockDim.x + threadIdx.x;
    if (i >= N_NODES * EMB) return;
    int n = i >> 5, c = i & 31;
    atomicMax(&pooledU[batch[n] * EMB + c], encf(h[i]));
}

// ---- head ----
__global__ void out_k(const unsigned* __restrict__ pooledU, const float* __restrict__ Wout,
                      const float* __restrict__ bout, float* __restrict__ out) {
    int i = blockIdx.x * blockDim.x + threadIdx.x;
    if (i >= NUM_GRAPHS * EMB) return;
    int g = i >> 5, c = i & 31;
    float v = decf(pooledU[i]);
    out[NUM_GRAPHS + i] = v;       // pooled output [1024,32]
    float p = v * Wout[c];
#pragma unroll
    for (int o = 16; o > 0; o >>= 1) p += __shfl_xor(p, o, 32);
    if (c == 0) out[g] = p + bout[0];
}

extern "C" void kernel_launch(void* const* d_in, const int* in_sizes, int n_in,
                              void* d_out, int out_size, void* d_ws, size_t ws_size,
                              hipStream_t stream) {
    const float* x     = (const float*)d_in[0];
    const int*   ei    = (const int*)d_in[1];     // [2, E]
    const int*   src   = ei;
    const int*   dst   = ei + N_EDGES;
    const int*   batch = (const int*)d_in[2];
    const float* W0    = (const float*)d_in[3];
    const float* b0    = (const float*)d_in[4];
    const float* Ws    = (const float*)d_in[5];
    const float* bs    = (const float*)d_in[6];
    const float* Wout  = (const float*)d_in[7];
    const float* bout  = (const float*)d_in[8];
    float* out = (float*)d_out;

    // workspace layout (aliasing keeps total == round-1 footprint)
    char* ws = (char*)d_ws;
    int*      row_ptr = (int*)ws;        ws += 400016;                        // N+1 ints, padded to 16B
    int*      col     = (int*)ws;        ws += (size_t)N_EDGES * 4;           // 12.8 MB
    float*    dinv    = (float*)ws;      ws += (size_t)N_NODES * 4;           // 400 KB
    float*    tmp     = (float*)ws;      ws += (size_t)N_NODES * EMB * 4;     // 12.8 MB
    float*    h       = (float*)ws;      ws += (size_t)N_NODES * EMB * 4;     // 12.8 MB
    unsigned* pooledU = (unsigned*)ws;   ws += (size_t)NUM_GRAPHS * EMB * 4;  // 128 KB
    int* deg = (int*)tmp;   // deg dead before transform0 writes tmp
    int* pos = (int*)h;     // pos dead before gather_k layer 0 writes h

    const int B = 256;
    const int NE_g = (N_EDGES + B - 1) / B;
    const int NC_g = (N_NODES * EMB + B - 1) / B;
    const int G8_g = (N_NODES * 8 + B - 1) / B;
    const int NN_g = (N_NODES + B - 1) / B;

    init_k<<<NN_g, B, 0, stream>>>(deg, pooledU);
    degree_k<<<NE_g, B, 0, stream>>>(dst, deg);
    scan_k<<<1, SCAN_T, 0, stream>>>(deg, row_ptr, pos, dinv);
    fill_k<<<NE_g, B, 0, stream>>>(src, dst, pos, col);

    // layer 0: 128 -> 32
    transform0_k<<<NC_g, B, 0, stream>>>(x, W0, dinv, tmp);
    gather_k<<<G8_g, B, 0, stream>>>(row_ptr, col, (const float4*)tmp, dinv, b0, (float4*)h);

    // hidden layers: 32 -> 32
    for (int l = 0; l < 3; ++l) {
        transform_k<<<NC_g, B, 0, stream>>>(h, Ws + l * EMB * EMB, dinv, tmp);
        gather_k<<<G8_g, B, 0, stream>>>(row_ptr, col, (const float4*)tmp, dinv,
                                         bs + l * EMB, (float4*)h);
    }

    pool_k<<<NC_g, B, 0, stream>>>(h, batch, pooledU);
    out_k<<<(NUM_GRAPHS * EMB + B - 1) / B, B, 0, stream>>>(pooledU, Wout, bout, out);
}

// Round 3
// 1064.426 us; speedup vs baseline: 5.2603x; 1.3226x over previous
//
#include <hip/hip_runtime.h>

#define N_NODES   100000
#define N_EDGES   3200000
#define NUM_GRAPHS 1024
#define F_IN      128
#define EMB       32

#define SCAN_TILE 1024                       // elems per scan block (256 thr x 4)
#define SCAN_NB   ((N_NODES + SCAN_TILE - 1) / SCAN_TILE)   // 98

// ---- init: zero degree counts; row_ptr[N] = E (constant, known) ----
__global__ void init_k(int* __restrict__ deg, int* __restrict__ row_ptr) {
    int i = blockIdx.x * blockDim.x + threadIdx.x;
    if (i < N_NODES) deg[i] = 0;
    if (i == 0) row_ptr[N_NODES] = N_EDGES;
}

// ---- degree: count incoming edges per node ----
__global__ void degree_k(const int* __restrict__ dst, int* __restrict__ deg) {
    int e = blockIdx.x * blockDim.x + threadIdx.x;
    if (e < N_EDGES) atomicAdd(&deg[dst[e]], 1);
}

// ---- scan phase 1: per-block (1024-elem tile) sum of deg ----
__global__ __launch_bounds__(256) void scan_reduce_k(const int* __restrict__ deg,
                                                     int* __restrict__ partial) {
    __shared__ int l[256];
    int b = blockIdx.x, t = threadIdx.x;
    int base = b * SCAN_TILE + t * 4;
    int s = 0;
    if (base + 3 < N_NODES) {
        int4 v = *(const int4*)(deg + base);
        s = v.x + v.y + v.z + v.w;
    } else {
        for (int i = 0; i < 4; ++i) if (base + i < N_NODES) s += deg[base + i];
    }
    l[t] = s; __syncthreads();
    for (int off = 128; off > 0; off >>= 1) {
        if (t < off) l[t] += l[t + off];
        __syncthreads();
    }
    if (t == 0) partial[b] = l[0];
}

// ---- scan phase 2: exclusive scan of the 98 partials (one small block) ----
__global__ __launch_bounds__(128) void scan_partials_k(const int* __restrict__ partial,
                                                       int* __restrict__ blockoff) {
    __shared__ int l[128];
    int t = threadIdx.x;
    l[t] = (t < SCAN_NB) ? partial[t] : 0;
    __syncthreads();
    for (int off = 1; off < 128; off <<= 1) {
        int v = l[t];
        int a = (t >= off) ? l[t - off] : 0;
        __syncthreads();
        l[t] = v + a;
        __syncthreads();
    }
    if (t < SCAN_NB) blockoff[t] = (t > 0) ? l[t - 1] : 0;
}

// ---- scan phase 3: apply — row_ptr / pos / dinv ----
__global__ __launch_bounds__(256) void scan_apply_k(const int* __restrict__ deg,
                                                    const int* __restrict__ blockoff,
                                                    int* __restrict__ row_ptr,
                                                    int* __restrict__ pos,
                                                    float* __restrict__ dinv) {
    __shared__ int l[256];
    int b = blockIdx.x, t = threadIdx.x;
    int base = b * SCAN_TILE + t * 4;
    int d0 = 0, d1 = 0, d2 = 0, d3 = 0;
    if (base + 3 < N_NODES) {
        int4 v = *(const int4*)(deg + base);
        d0 = v.x; d1 = v.y; d2 = v.z; d3 = v.w;
    } else {
        if (base + 0 < N_NODES) d0 = deg[base + 0];
        if (base + 1 < N_NODES) d1 = deg[base + 1];
        if (base + 2 < N_NODES) d2 = deg[base + 2];
        if (base + 3 < N_NODES) d3 = deg[base + 3];
    }
    l[t] = d0 + d1 + d2 + d3;
    __syncthreads();
    for (int off = 1; off < 256; off <<= 1) {
        int v = l[t];
        int a = (t >= off) ? l[t - off] : 0;
        __syncthreads();
        l[t] = v + a;
        __syncthreads();
    }
    int run = blockoff[b] + ((t > 0) ? l[t - 1] : 0);
    if (base + 0 < N_NODES) { row_ptr[base + 0] = run; pos[base + 0] = run; dinv[base + 0] = rsqrtf((float)(d0 + 1)); run += d0; }
    if (base + 1 < N_NODES) { row_ptr[base + 1] = run; pos[base + 1] = run; dinv[base + 1] = rsqrtf((float)(d1 + 1)); run += d1; }
    if (base + 2 < N_NODES) { row_ptr[base + 2] = run; pos[base + 2] = run; dinv[base + 2] = rsqrtf((float)(d2 + 1)); run += d2; }
    if (base + 3 < N_NODES) { row_ptr[base + 3] = run; pos[base + 3] = run; dinv[base + 3] = rsqrtf((float)(d3 + 1)); run += d3; }
}

// ---- CSR fill: col[pos[dst[e]]++] = src[e] ----
__global__ void fill_k(const int* __restrict__ src, const int* __restrict__ dst,
                       int* __restrict__ pos, int* __restrict__ col) {
    int e = blockIdx.x * blockDim.x + threadIdx.x;
    if (e < N_EDGES) {
        int idx = atomicAdd(&pos[dst[e]], 1);
        col[idx] = src[e];
    }
}

// ---- layer 0 transform: tmp[n][j] = (x[n,:] @ W0[:,j]) * dinv[n] ----
__global__ void transform0_k(const float* __restrict__ x, const float* __restrict__ W0,
                             const float* __restrict__ dinv, float* __restrict__ tmp) {
    int i = blockIdx.x * blockDim.x + threadIdx.x;
    if (i >= N_NODES * EMB) return;
    int n = i >> 5, j = i & 31;
    const float* xr = x + (long long)n * F_IN;
    float acc = 0.f;
#pragma unroll 8
    for (int k = 0; k < F_IN; ++k) acc += xr[k] * W0[k * EMB + j];
    tmp[i] = acc * dinv[n];
}

// ---- hidden transform: tmp[n][j] = (h[n,:] @ W[:,j]) * dinv[n] ----
__global__ void transform_k(const float* __restrict__ h, const float* __restrict__ W,
                            const float* __restrict__ dinv, float* __restrict__ tmp) {
    int i = blockIdx.x * blockDim.x + threadIdx.x;
    if (i >= N_NODES * EMB) return;
    int n = i >> 5, j = i & 31;
    const float* hr = h + n * EMB;
    float acc = 0.f;
#pragma unroll
    for (int k = 0; k < EMB; ++k) acc += hr[k] * W[k * EMB + j];
    tmp[i] = acc * dinv[n];
}

// ---- gather aggregate + finalize: h = leaky(dinv[n]*(tmp[n] + sum_in tmp[s]) + b) ----
__global__ void gather_k(const int* __restrict__ row_ptr, const int* __restrict__ col,
                         const float4* __restrict__ tmp4, const float* __restrict__ dinv,
                         const float* __restrict__ b, float4* __restrict__ h4) {
    int i = blockIdx.x * blockDim.x + threadIdx.x;
    if (i >= N_NODES * 8) return;
    int n = i >> 3, q = i & 7;
    int beg = row_ptr[n], end = row_ptr[n + 1];
    float4 acc = tmp4[i];              // self-loop term
    int k = beg;
    for (; k + 4 <= end; k += 4) {
        int s0 = col[k], s1 = col[k + 1], s2 = col[k + 2], s3 = col[k + 3];
        float4 v0 = tmp4[s0 * 8 + q];
        float4 v1 = tmp4[s1 * 8 + q];
        float4 v2 = tmp4[s2 * 8 + q];
        float4 v3 = tmp4[s3 * 8 + q];
        acc.x += (v0.x + v1.x) + (v2.x + v3.x);
        acc.y += (v0.y + v1.y) + (v2.y + v3.y);
        acc.z += (v0.z + v1.z) + (v2.z + v3.z);
        acc.w += (v0.w + v1.w) + (v2.w + v3.w);
    }
    for (; k < end; ++k) {
        int s = col[k];
        float4 v = tmp4[s * 8 + q];
        acc.x += v.x; acc.y += v.y; acc.z += v.z; acc.w += v.w;
    }
    float dn = dinv[n];
    float4 bb = ((const float4*)b)[q];
    float4 r;
    r.x = acc.x * dn + bb.x;
    r.y = acc.y * dn + bb.y;
    r.z = acc.z * dn + bb.z;
    r.w = acc.w * dn + bb.w;
    r.x = r.x > 0.f ? r.x : 0.01f * r.x;
    r.y = r.y > 0.f ? r.y : 0.01f * r.y;
    r.z = r.z > 0.f ? r.z : 0.01f * r.z;
    r.w = r.w > 0.f ? r.w : 0.01f * r.w;
    h4[i] = r;
}

// ---- fused pool + head: one block per graph (batch_index is sorted) ----
__global__ __launch_bounds__(256) void pool_head_k(const float* __restrict__ h,
                                                   const int* __restrict__ batch,
                                                   const float* __restrict__ Wout,
                                                   const float* __restrict__ bout,
                                                   float* __restrict__ out) {
    int g = blockIdx.x;
    __shared__ int sbeg, send;
    if (threadIdx.x == 0) {
        int lo = 0, hi = N_NODES;
        while (lo < hi) { int mid = (lo + hi) >> 1; if (batch[mid] < g) lo = mid + 1; else hi = mid; }
        sbeg = lo;
        hi = N_NODES;
        while (lo < hi) { int mid = (lo + hi) >> 1; if (batch[mid] < g + 1) lo = mid + 1; else hi = mid; }
        send = lo;
    }
    __syncthreads();
    int beg = sbeg, end = send;
    int t = threadIdx.x, c = t & 31, r = t >> 5;   // 8 node-lanes x 32 channels
    float m = -INFINITY;
    for (int n = beg + r; n < end; n += 8) m = fmaxf(m, h[n * EMB + c]);
    __shared__ float red[256];
    red[t] = m;
    __syncthreads();
    if (t < 128) red[t] = fmaxf(red[t], red[t + 128]);
    __syncthreads();
    if (t < 64) red[t] = fmaxf(red[t], red[t + 64]);
    __syncthreads();
    if (t < 32) {
        m = fmaxf(red[t], red[t + 32]);
        out[NUM_GRAPHS + g * EMB + c] = m;      // pooled [1024,32]
        float p = m * Wout[c];
#pragma unroll
        for (int o = 16; o > 0; o >>= 1) p += __shfl_xor(p, o, 32);
        if (c == 0) out[g] = p + bout[0];
    }
}

extern "C" void kernel_launch(void* const* d_in, const int* in_sizes, int n_in,
                              void* d_out, int out_size, void* d_ws, size_t ws_size,
                              hipStream_t stream) {
    const float* x     = (const float*)d_in[0];
    const int*   ei    = (const int*)d_in[1];     // [2, E]
    const int*   src   = ei;
    const int*   dst   = ei + N_EDGES;
    const int*   batch = (const int*)d_in[2];
    const float* W0    = (const float*)d_in[3];
    const float* b0    = (const float*)d_in[4];
    const float* Ws    = (const float*)d_in[5];
    const float* bs    = (const float*)d_in[6];
    const float* Wout  = (const float*)d_in[7];
    const float* bout  = (const float*)d_in[8];
    float* out = (float*)d_out;

    char* ws = (char*)d_ws;
    int*   row_ptr  = (int*)ws;   ws += 400016;                        // N+1 ints, 16B-padded
    int*   col      = (int*)ws;   ws += (size_t)N_EDGES * 4;           // 12.8 MB
    float* dinv     = (float*)ws; ws += (size_t)N_NODES * 4;           // 400 KB
    float* tmp      = (float*)ws; ws += (size_t)N_NODES * EMB * 4;     // 12.8 MB
    float* h        = (float*)ws; ws += (size_t)N_NODES * EMB * 4;     // 12.8 MB
    int*   partial  = (int*)ws;   ws += 512;                           // 98 ints
    int*   blockoff = (int*)ws;   ws += 512;                           // 98 ints
    int* deg = (int*)tmp;   // deg dead once scan_apply_k finishes (before transform0 writes tmp)
    int* pos = (int*)h;     // pos dead once fill_k finishes (before gather layer 0 writes h)

    const int B = 256;
    const int NE_g = (N_EDGES + B - 1) / B;
    const int NC_g = (N_NODES * EMB + B - 1) / B;
    const int G8_g = (N_NODES * 8 + B - 1) / B;
    const int NN_g = (N_NODES + B - 1) / B;

    init_k<<<NN_g, B, 0, stream>>>(deg, row_ptr);
    degree_k<<<NE_g, B, 0, stream>>>(dst, deg);
    scan_reduce_k<<<SCAN_NB, 256, 0, stream>>>(deg, partial);
    scan_partials_k<<<1, 128, 0, stream>>>(partial, blockoff);
    scan_apply_k<<<SCAN_NB, 256, 0, stream>>>(deg, blockoff, row_ptr, pos, dinv);
    fill_k<<<NE_g, B, 0, stream>>>(src, dst, pos, col);

    // layer 0: 128 -> 32
    transform0_k<<<NC_g, B, 0, stream>>>(x, W0, dinv, tmp);
    gather_k<<<G8_g, B, 0, stream>>>(row_ptr, col, (const float4*)tmp, dinv, b0, (float4*)h);

    // hidden layers: 32 -> 32
    for (int l = 0; l < 3; ++l) {
        transform_k<<<NC_g, B, 0, stream>>>(h, Ws + l * EMB * EMB, dinv, tmp);
        gather_k<<<G8_g, B, 0, stream>>>(row_ptr, col, (const float4*)tmp, dinv,
                                         bs + l * EMB, (float4*)h);
    }

    pool_head_k<<<NUM_GRAPHS, 256, 0, stream>>>(h, batch, Wout, bout, out);
}

// Round 4
// 885.145 us; speedup vs baseline: 6.3258x; 1.2025x over previous
//
#include <hip/hip_runtime.h>

#define N_NODES   100000
#define N_EDGES   3200000
#define NUM_GRAPHS 1024
#define F_IN      128
#define EMB       32

#define NRANGE    4
#define RANGE_SZ  25000                    // N_NODES / NRANGE (src ranges)
#define NKEY      (N_NODES * NRANGE)       // 400000 CSR buckets (dst*4 + srcRange)
#define NGROUP    8                        // dst groups (one per XCD)
#define GROUP_SZ  12500                    // N_NODES / NGROUP
#define FILL_CHUNKS 128
#define CHUNK_SZ  25000                    // N_EDGES / FILL_CHUNKS (exact)

#define SCAN_TILE 1024                     // elems per scan block (256 thr x int4)
#define SCAN_NB   ((NKEY + SCAN_TILE - 1) / SCAN_TILE)   // 391

// ---- init: zero per-key degree counts; rp2[NKEY] = E sentinel ----
__global__ void init_k(int* __restrict__ deg2, int* __restrict__ rp2) {
    int i = blockIdx.x * blockDim.x + threadIdx.x;
    if (i < NKEY) deg2[i] = 0;
    if (i == 0) rp2[NKEY] = N_EDGES;
}

// ---- degree over (dst, srcRange) keys ----
__global__ void degree_k(const int* __restrict__ src, const int* __restrict__ dst,
                         int* __restrict__ deg2) {
    int e = blockIdx.x * blockDim.x + threadIdx.x;
    if (e < N_EDGES) {
        unsigned d = (unsigned)dst[e], s = (unsigned)src[e];
        atomicAdd(&deg2[d * NRANGE + s / RANGE_SZ], 1);
    }
}

// ---- scan phase 1: per-tile sums ----
__global__ __launch_bounds__(256) void scan_reduce_k(const int* __restrict__ deg2,
                                                     int* __restrict__ partial) {
    __shared__ int l[256];
    int b = blockIdx.x, t = threadIdx.x;
    int base = b * SCAN_TILE + t * 4;
    int s = 0;
    if (base < NKEY) {                      // NKEY % 4 == 0 -> full int4 or nothing
        int4 v = *(const int4*)(deg2 + base);
        s = v.x + v.y + v.z + v.w;
    }
    l[t] = s; __syncthreads();
    for (int off = 128; off > 0; off >>= 1) {
        if (t < off) l[t] += l[t + off];
        __syncthreads();
    }
    if (t == 0) partial[b] = l[0];
}

// ---- scan phase 2: exclusive scan of 391 partials ----
__global__ __launch_bounds__(512) void scan_partials_k(const int* __restrict__ partial,
                                                       int* __restrict__ blockoff) {
    __shared__ int l[512];
    int t = threadIdx.x;
    l[t] = (t < SCAN_NB) ? partial[t] : 0;
    __syncthreads();
    for (int off = 1; off < 512; off <<= 1) {
        int v = l[t];
        int a = (t >= off) ? l[t - off] : 0;
        __syncthreads();
        l[t] = v + a;
        __syncthreads();
    }
    if (t < SCAN_NB) blockoff[t] = (t > 0) ? l[t - 1] : 0;
}

// ---- scan phase 3: apply -> rp2 / pos2 / dinv (4 keys per thread = 1 node) ----
__global__ __launch_bounds__(256) void scan_apply_k(const int* __restrict__ deg2,
                                                    const int* __restrict__ blockoff,
                                                    int* __restrict__ rp2,
                                                    int* __restrict__ pos2,
                                                    float* __restrict__ dinv) {
    __shared__ int l[256];
    int b = blockIdx.x, t = threadIdx.x;
    int base = b * SCAN_TILE + t * 4;
    int d0 = 0, d1 = 0, d2 = 0, d3 = 0;
    if (base < NKEY) {
        int4 v = *(const int4*)(deg2 + base);
        d0 = v.x; d1 = v.y; d2 = v.z; d3 = v.w;
    }
    l[t] = d0 + d1 + d2 + d3;
    __syncthreads();
    for (int off = 1; off < 256; off <<= 1) {
        int v = l[t];
        int a = (t >= off) ? l[t - off] : 0;
        __syncthreads();
        l[t] = v + a;
        __syncthreads();
    }
    if (base < NKEY) {
        int run = blockoff[b] + ((t > 0) ? l[t - 1] : 0);
        int node = base >> 2;               // 4 consecutive keys = one node
        dinv[node] = rsqrtf((float)(d0 + d1 + d2 + d3 + 1));
        rp2[base + 0] = run; pos2[base + 0] = run; run += d0;
        rp2[base + 1] = run; pos2[base + 1] = run; run += d1;
        rp2[base + 2] = run; pos2[base + 2] = run; run += d2;
        rp2[base + 3] = run; pos2[base + 3] = run; run += d3;
    }
}

// ---- XCD-local CSR fill: block group g (= blockIdx & 7) handles dst in its range only ----
__global__ __launch_bounds__(256) void fill_k(const int* __restrict__ src,
                                              const int* __restrict__ dst,
                                              int* __restrict__ pos2,
                                              int* __restrict__ col) {
    int b = blockIdx.x;
    unsigned g = (unsigned)(b & (NGROUP - 1));   // XCD round-robin bet
    int cid = b >> 3;
    int beg = cid * CHUNK_SZ, end = beg + CHUNK_SZ;   // exact partition
    for (int e = beg + threadIdx.x; e < end; e += 256) {
        unsigned d = (unsigned)dst[e];
        if (d / GROUP_SZ != g) continue;
        unsigned s = (unsigned)src[e];
        int slot = atomicAdd(&pos2[d * NRANGE + s / RANGE_SZ], 1);
        col[slot] = (int)s;
    }
}

// ---- layer 0 transform: tmp[n][j] = (x[n,:] @ W0[:,j]) * dinv[n] ----
__global__ void transform0_k(const float* __restrict__ x, const float* __restrict__ W0,
                             const float* __restrict__ dinv, float* __restrict__ tmp) {
    int i = blockIdx.x * blockDim.x + threadIdx.x;
    if (i >= N_NODES * EMB) return;
    int n = i >> 5, j = i & 31;
    const float* xr = x + (long long)n * F_IN;
    float acc = 0.f;
#pragma unroll 8
    for (int k = 0; k < F_IN; ++k) acc += xr[k] * W0[k * EMB + j];
    tmp[i] = acc * dinv[n];
}

// ---- hidden transform: tmp[n][j] = (h[n,:] @ W[:,j]) * dinv[n] ----
__global__ void transform_k(const float* __restrict__ h, const float* __restrict__ W,
                            const float* __restrict__ dinv, float* __restrict__ tmp) {
    int i = blockIdx.x * blockDim.x + threadIdx.x;
    if (i >= N_NODES * EMB) return;
    int n = i >> 5, j = i & 31;
    const float* hr = h + n * EMB;
    float acc = 0.f;
#pragma unroll
    for (int k = 0; k < EMB; ++k) acc += hr[k] * W[k * EMB + j];
    tmp[i] = acc * dinv[n];
}

// ---- phased gather: phase r touches only tmp slice [r*25000, (r+1)*25000) ----
// MODE 0: acc = tmp (self-loop) + range sum; MODE 1: acc = h + range sum;
// MODE 2: like 1, then finalize (dinv scale, bias, leaky-relu).
template <int MODE>
__global__ void gatherp_k(const int* __restrict__ rp2, const int* __restrict__ col,
                          const float4* __restrict__ tmp4, const float* __restrict__ dinv,
                          const float* __restrict__ bias, float4* __restrict__ h4, int r) {
    int i = blockIdx.x * blockDim.x + threadIdx.x;
    if (i >= N_NODES * 8) return;
    int n = i >> 3, q = i & 7;
    int beg = rp2[n * 4 + r], end = rp2[n * 4 + r + 1];
    float4 acc = (MODE == 0) ? tmp4[i] : h4[i];
    int k = beg;
    for (; k + 4 <= end; k += 4) {
        int s0 = col[k], s1 = col[k + 1], s2 = col[k + 2], s3 = col[k + 3];
        float4 v0 = tmp4[s0 * 8 + q];
        float4 v1 = tmp4[s1 * 8 + q];
        float4 v2 = tmp4[s2 * 8 + q];
        float4 v3 = tmp4[s3 * 8 + q];
        acc.x += (v0.x + v1.x) + (v2.x + v3.x);
        acc.y += (v0.y + v1.y) + (v2.y + v3.y);
        acc.z += (v0.z + v1.z) + (v2.z + v3.z);
        acc.w += (v0.w + v1.w) + (v2.w + v3.w);
    }
    for (; k < end; ++k) {
        int s = col[k];
        float4 v = tmp4[s * 8 + q];
        acc.x += v.x; acc.y += v.y; acc.z += v.z; acc.w += v.w;
    }
    if (MODE == 2) {
        float dn = dinv[n];
        float4 bb = ((const float4*)bias)[q];
        float4 rr;
        rr.x = acc.x * dn + bb.x;
        rr.y = acc.y * dn + bb.y;
        rr.z = acc.z * dn + bb.z;
        rr.w = acc.w * dn + bb.w;
        rr.x = rr.x > 0.f ? rr.x : 0.01f * rr.x;
        rr.y = rr.y > 0.f ? rr.y : 0.01f * rr.y;
        rr.z = rr.z > 0.f ? rr.z : 0.01f * rr.z;
        rr.w = rr.w > 0.f ? rr.w : 0.01f * rr.w;
        h4[i] = rr;
    } else {
        h4[i] = acc;
    }
}

// ---- fused pool + head: one block per graph (batch_index is sorted) ----
__global__ __launch_bounds__(256) void pool_head_k(const float* __restrict__ h,
                                                   const int* __restrict__ batch,
                                                   const float* __restrict__ Wout,
                                                   const float* __restrict__ bout,
                                                   float* __restrict__ out) {
    int g = blockIdx.x;
    __shared__ int sbeg, send;
    if (threadIdx.x == 0) {
        int lo = 0, hi = N_NODES;
        while (lo < hi) { int mid = (lo + hi) >> 1; if (batch[mid] < g) lo = mid + 1; else hi = mid; }
        sbeg = lo;
        hi = N_NODES;
        while (lo < hi) { int mid = (lo + hi) >> 1; if (batch[mid] < g + 1) lo = mid + 1; else hi = mid; }
        send = lo;
    }
    __syncthreads();
    int beg = sbeg, end = send;
    int t = threadIdx.x, c = t & 31, r = t >> 5;
    float m = -INFINITY;
    for (int n = beg + r; n < end; n += 8) m = fmaxf(m, h[n * EMB + c]);
    __shared__ float red[256];
    red[t] = m;
    __syncthreads();
    if (t < 128) red[t] = fmaxf(red[t], red[t + 128]);
    __syncthreads();
    if (t < 64) red[t] = fmaxf(red[t], red[t + 64]);
    __syncthreads();
    if (t < 32) {
        m = fmaxf(red[t], red[t + 32]);
        out[NUM_GRAPHS + g * EMB + c] = m;
        float p = m * Wout[c];
#pragma unroll
        for (int o = 16; o > 0; o >>= 1) p += __shfl_xor(p, o, 32);
        if (c == 0) out[g] = p + bout[0];
    }
}

extern "C" void kernel_launch(void* const* d_in, const int* in_sizes, int n_in,
                              void* d_out, int out_size, void* d_ws, size_t ws_size,
                              hipStream_t stream) {
    const float* x     = (const float*)d_in[0];
    const int*   ei    = (const int*)d_in[1];
    const int*   src   = ei;
    const int*   dst   = ei + N_EDGES;
    const int*   batch = (const int*)d_in[2];
    const float* W0    = (const float*)d_in[3];
    const float* b0    = (const float*)d_in[4];
    const float* Ws    = (const float*)d_in[5];
    const float* bs    = (const float*)d_in[6];
    const float* Wout  = (const float*)d_in[7];
    const float* bout  = (const float*)d_in[8];
    float* out = (float*)d_out;

    char* ws = (char*)d_ws;
    int*   rp2      = (int*)ws;   ws += (size_t)(NKEY + 4) * 4;        // 400001 ints, padded
    int*   col      = (int*)ws;   ws += (size_t)N_EDGES * 4;           // 12.8 MB
    float* dinv     = (float*)ws; ws += (size_t)N_NODES * 4;           // 400 KB
    float* tmp      = (float*)ws; ws += (size_t)N_NODES * EMB * 4;     // 12.8 MB
    float* h        = (float*)ws; ws += (size_t)N_NODES * EMB * 4;     // 12.8 MB
    int*   partial  = (int*)ws;   ws += 2048;                          // 391 ints
    int*   blockoff = (int*)ws;   ws += 2048;                          // 391 ints
    int* deg2 = (int*)tmp;   // dead before transform0 writes tmp
    int* pos2 = (int*)h;     // dead before gather phase 0 writes h

    const int B = 256;
    const int NE_g = (N_EDGES + B - 1) / B;
    const int NC_g = (N_NODES * EMB + B - 1) / B;
    const int G8_g = (N_NODES * 8 + B - 1) / B;
    const int NK_g = (NKEY + B - 1) / B;

    init_k<<<NK_g, B, 0, stream>>>(deg2, rp2);
    degree_k<<<NE_g, B, 0, stream>>>(src, dst, deg2);
    scan_reduce_k<<<SCAN_NB, B, 0, stream>>>(deg2, partial);
    scan_partials_k<<<1, 512, 0, stream>>>(partial, blockoff);
    scan_apply_k<<<SCAN_NB, B, 0, stream>>>(deg2, blockoff, rp2, pos2, dinv);
    fill_k<<<NGROUP * FILL_CHUNKS, B, 0, stream>>>(src, dst, pos2, col);

    // layer 0: 128 -> 32
    transform0_k<<<NC_g, B, 0, stream>>>(x, W0, dinv, tmp);
    gatherp_k<0><<<G8_g, B, 0, stream>>>(rp2, col, (const float4*)tmp, dinv, b0, (float4*)h, 0);
    gatherp_k<1><<<G8_g, B, 0, stream>>>(rp2, col, (const float4*)tmp, dinv, b0, (float4*)h, 1);
    gatherp_k<1><<<G8_g, B, 0, stream>>>(rp2, col, (const float4*)tmp, dinv, b0, (float4*)h, 2);
    gatherp_k<2><<<G8_g, B, 0, stream>>>(rp2, col, (const float4*)tmp, dinv, b0, (float4*)h, 3);

    // hidden layers: 32 -> 32
    for (int l = 0; l < 3; ++l) {
        const float* bl = bs + l * EMB;
        transform_k<<<NC_g, B, 0, stream>>>(h, Ws + l * EMB * EMB, dinv, tmp);
        gatherp_k<0><<<G8_g, B, 0, stream>>>(rp2, col, (const float4*)tmp, dinv, bl, (float4*)h, 0);
        gatherp_k<1><<<G8_g, B, 0, stream>>>(rp2, col, (const float4*)tmp, dinv, bl, (float4*)h, 1);
        gatherp_k<1><<<G8_g, B, 0, stream>>>(rp2, col, (const float4*)tmp, dinv, bl, (float4*)h, 2);
        gatherp_k<2><<<G8_g, B, 0, stream>>>(rp2, col, (const float4*)tmp, dinv, bl, (float4*)h, 3);
    }

    pool_head_k<<<NUM_GRAPHS, B, 0, stream>>>(h, batch, Wout, bout, out);
}